// Round 9
// baseline (1083.928 us; speedup 1.0000x reference)
//
#include <hip/hip_runtime.h>
#include <hip/hip_bf16.h>

typedef __attribute__((ext_vector_type(8))) short s16x8;
typedef __attribute__((ext_vector_type(4))) float f32x4;
typedef __attribute__((ext_vector_type(4))) unsigned short us4;

#define DI __device__ __forceinline__

DI float b2f(unsigned short u){ union{float f; unsigned int i;} v; v.i = ((unsigned int)u)<<16; return v.f; }
DI unsigned short f2b(float f){ union{float f; unsigned int i;} v; v.f = f; unsigned int r = v.i + 0x7FFF + ((v.i>>16)&1u); return (unsigned short)(r>>16); }
DI float geluf(float x){ return 0.5f*x*(1.f + erff(x*0.70710678118654752f)); }
DI float sigmf(float x){ return 1.f/(1.f + expf(-x)); }

#define MFMA(a,b,c) __builtin_amdgcn_mfma_f32_16x16x32_bf16((a),(b),(c),0,0,0)

// ---------------- zero workspace (determinism armor) ----------------
__global__ __launch_bounds__(256) void k_zero(float* __restrict__ w){
  int idx = blockIdx.x*256 + threadIdx.x;
  *(f32x4*)(w + (long)idx*4) = (f32x4){0.f,0.f,0.f,0.f};
}

// ---------------- hi/lo split repack (K x M row-major fp32 -> bf16 MFMA A-frag layout) ----------------
__global__ __launch_bounds__(256) void k_repack2(const float* __restrict__ W,
                                                 unsigned short* __restrict__ oh,
                                                 unsigned short* __restrict__ ol,
                                                 int M, int ktlog2, int nthreads){
  int idx = blockIdx.x*256 + threadIdx.x;
  if(idx >= nthreads) return;
  int lane = idx & 63;
  int kt   = (idx>>6) & ((1<<ktlog2)-1);
  int mt   = idx >> (6+ktlog2);
  int k0 = kt*32 + (lane>>4)*8;
  int m  = mt*16 + (lane&15);
  s16x8 vh, vl;
  for(int j=0;j<8;j++){
    float v = W[(k0+j)*M + m];
    unsigned short h = f2b(v);
    vh[j] = (short)h;
    vl[j] = (short)f2b(v - b2f(h));
  }
  *(s16x8*)(oh + (long)idx*8) = vh;
  *(s16x8*)(ol + (long)idx*8) = vl;
}

// ---------------- transpose repack: t5WT[m*128+k] = t5W[k*128+m] ----------------
__global__ __launch_bounds__(256) void k_repackT(const float* __restrict__ W,
                                                 float* __restrict__ out){
  int idx = blockIdx.x*256 + threadIdx.x;   // 0..16383
  int m = idx>>7, k = idx&127;
  out[idx] = W[k*128 + m];
}

// ---------------- K1: xn = LN(x, n2) fp32 (two-pass) ----------------
__global__ __launch_bounds__(256) void k1_ln(const float* __restrict__ x,
                                             const float* __restrict__ s,
                                             const float* __restrict__ b,
                                             float* __restrict__ xn){
  int row = blockIdx.x, t = threadIdx.x;
  const float* xr = x + row*512;
  float v0 = xr[t], v1 = xr[t+256];
  float sum = v0+v1;
  for(int o=32;o>=1;o>>=1) sum += __shfl_down(sum,o);
  __shared__ float ls[4], lq[4];
  int w = t>>6;
  if((t&63)==0) ls[w]=sum;
  __syncthreads();
  float m = (ls[0]+ls[1]+ls[2]+ls[3])*(1.f/512.f);
  float d0 = v0-m, d1 = v1-m;
  float sq = d0*d0 + d1*d1;
  for(int o=32;o>=1;o>>=1) sq += __shfl_down(sq,o);
  if((t&63)==0) lq[w]=sq;
  __syncthreads();
  float rstd = rsqrtf((lq[0]+lq[1]+lq[2]+lq[3])*(1.f/512.f) + 1e-5f);
  xn[row*512+t]     = d0*rstd*s[t]     + b[t];
  xn[row*512+t+256] = d1*rstd*s[t+256] + b[t+256];
}

// ---------------- K2: h = gelu(xn @ nffn1_W + b1)  PURE FP32 ----------------
// block = 16 rows x 128 cols; W1 [512 x 2048] row-major; grid (16, 32)
__global__ __launch_bounds__(256) void k2_f32(const float* __restrict__ xn,
                                              const float* __restrict__ W1,
                                              const float* __restrict__ b1,
                                              float* __restrict__ h){
  __shared__ __align__(16) float As[16*520];
  int t = threadIdx.x;
  int rowbase = blockIdx.y*16;
  int colbase = blockIdx.x*128;
  for(int k=0;k<8;k++){
    int v4 = t + k*256;            // 0..2047 vecs
    int r = v4>>7, c4 = v4&127;
    *(f32x4*)&As[r*520 + c4*4] = *(const f32x4*)(xn + (rowbase+r)*512 + c4*4);
  }
  __syncthreads();
  int r = t>>4, cg = t&15;
  int col0 = colbase + cg*8;
  float acc[8] = {0.f,0.f,0.f,0.f,0.f,0.f,0.f,0.f};
  for(int k=0;k<512;k++){
    float a = As[r*520+k];
    f32x4 w0 = *(const f32x4*)(W1 + (long)k*2048 + col0);
    f32x4 w1 = *(const f32x4*)(W1 + (long)k*2048 + col0 + 4);
    acc[0]+=a*w0[0]; acc[1]+=a*w0[1]; acc[2]+=a*w0[2]; acc[3]+=a*w0[3];
    acc[4]+=a*w1[0]; acc[5]+=a*w1[1]; acc[6]+=a*w1[2]; acc[7]+=a*w1[3];
  }
  f32x4 o0, o1v;
  for(int j=0;j<4;j++){ o0[j]  = geluf(acc[j]   + b1[col0+j]);
                        o1v[j] = geluf(acc[4+j] + b1[col0+4+j]); }
  *(f32x4*)(h + (long)(rowbase+r)*2048 + col0)     = o0;
  *(f32x4*)(h + (long)(rowbase+r)*2048 + col0 + 4) = o1v;
}

// ---------------- K3: xout = x + h @ nffn2_W + b2  PURE FP32 ----------------
// block = 16 rows x 128 cols; W2 [2048 x 512]; K chunked 4 x 512; grid (4, 32)
__global__ __launch_bounds__(256) void k3_f32(const float* __restrict__ h,
                                              const float* __restrict__ W2,
                                              const float* __restrict__ b2,
                                              const float* __restrict__ x,
                                              float* __restrict__ xout){
  __shared__ __align__(16) float As[16*520];
  int t = threadIdx.x;
  int rowbase = blockIdx.y*16;
  int colbase = blockIdx.x*128;
  int r = t>>4, cg = t&15;
  int col0 = colbase + cg*8;
  float acc[8] = {0.f,0.f,0.f,0.f,0.f,0.f,0.f,0.f};
  for(int kc=0;kc<4;kc++){
    __syncthreads();
    for(int k=0;k<8;k++){
      int v4 = t + k*256;
      int rr = v4>>7, c4 = v4&127;
      *(f32x4*)&As[rr*520 + c4*4] = *(const f32x4*)(h + (long)(rowbase+rr)*2048 + kc*512 + c4*4);
    }
    __syncthreads();
    for(int k=0;k<512;k++){
      float a = As[r*520+k];
      f32x4 w0 = *(const f32x4*)(W2 + (long)(kc*512+k)*512 + col0);
      f32x4 w1 = *(const f32x4*)(W2 + (long)(kc*512+k)*512 + col0 + 4);
      acc[0]+=a*w0[0]; acc[1]+=a*w0[1]; acc[2]+=a*w0[2]; acc[3]+=a*w0[3];
      acc[4]+=a*w1[0]; acc[5]+=a*w1[1]; acc[6]+=a*w1[2]; acc[7]+=a*w1[3];
    }
  }
  f32x4 xv0 = *(const f32x4*)(x + (long)(rowbase+r)*512 + col0);
  f32x4 xv1 = *(const f32x4*)(x + (long)(rowbase+r)*512 + col0 + 4);
  f32x4 o0, o1v;
  for(int j=0;j<4;j++){ o0[j]  = xv0[j] + acc[j]   + b2[col0+j];
                        o1v[j] = xv1[j] + acc[4+j] + b2[col0+4+j]; }
  *(f32x4*)(xout + (long)(rowbase+r)*512 + col0)     = o0;
  *(f32x4*)(xout + (long)(rowbase+r)*512 + col0 + 4) = o1v;
}

// ---------------- K4: o = LN(x_out,en1) @ o12_W + o12_b -> o1,o2 (fp32, two-pass LN) ----------------
__global__ __launch_bounds__(256) void k4_o12(const float* __restrict__ xout,
                                              const float* __restrict__ s,
                                              const float* __restrict__ b,
                                              const float* __restrict__ o12W,
                                              const float* __restrict__ o12b,
                                              float* __restrict__ o1, float* __restrict__ o2){
  int row = blockIdx.x, t = threadIdx.x;
  const float* xr = xout + row*512;
  float v0 = xr[t], v1 = xr[t+256];
  float sum = v0+v1;
  for(int o=32;o>=1;o>>=1) sum += __shfl_down(sum,o);
  __shared__ float ls[4], lq[4];
  __shared__ float red[4][8];
  int w = t>>6;
  if((t&63)==0) ls[w]=sum;
  __syncthreads();
  float m = (ls[0]+ls[1]+ls[2]+ls[3])*(1.f/512.f);
  float d0 = v0-m, d1 = v1-m;
  float sq = d0*d0 + d1*d1;
  for(int o=32;o>=1;o>>=1) sq += __shfl_down(sq,o);
  if((t&63)==0) lq[w]=sq;
  __syncthreads();
  float rstd = rsqrtf((lq[0]+lq[1]+lq[2]+lq[3])*(1.f/512.f) + 1e-5f);
  float x0 = d0*rstd*s[t]     + b[t];
  float x1 = d1*rstd*s[t+256] + b[t+256];
  f32x4 w0a = *(const f32x4*)(o12W + t*8);
  f32x4 w0b = *(const f32x4*)(o12W + t*8 + 4);
  f32x4 w1a = *(const f32x4*)(o12W + (t+256)*8), w1b = *(const f32x4*)(o12W + (t+256)*8 + 4);
  float pa[8];
  for(int r=0;r<4;r++){ pa[r]   = x0*w0a[r] + x1*w1a[r];
                        pa[4+r] = x0*w0b[r] + x1*w1b[r]; }
  for(int o=32;o>=1;o>>=1) for(int k=0;k<8;k++) pa[k] += __shfl_down(pa[k],o);
  if((t&63)==0) for(int k=0;k<8;k++) red[w][k] = pa[k];
  __syncthreads();
  if(t<8){
    float tot = red[0][t]+red[1][t]+red[2][t]+red[3][t] + o12b[t];
    if(t<4) o1[row*4+t] = tot; else o2[row*4+(t-4)] = tot;
  }
}

// ---------------- K5: p1 = p + outer(o1[i],o2[j]) @ o3_W + o3_b (fp32) ----------------
__global__ __launch_bounds__(256) void k5_p1(const float* __restrict__ p,
                                             const float* __restrict__ o3W,
                                             const float* __restrict__ o3b,
                                             const float* __restrict__ o1,
                                             const float* __restrict__ o2,
                                             float* __restrict__ p1){
  __shared__ float w_s[2048];
  __shared__ float b_s[128];
  int t = threadIdx.x;
  for(int r=0;r<8;r++) w_s[t*8+r] = o3W[t*8+r];
  if(t<128) b_s[t] = o3b[t];
  __syncthreads();
  int g = blockIdx.x*16 + (t>>4);
  int e0 = (t&15)*8;
  int bb = g>>16, ii = (g>>8)&255, jj = g&255;
  const float* o1p = o1 + (bb*256+ii)*4;
  const float* o2p = o2 + (bb*256+jj)*4;
  float c[16];
  for(int h=0;h<4;h++) for(int g2=0;g2<4;g2++) c[h*4+g2] = o1p[h]*o2p[g2];
  f32x4 pv0 = *(const f32x4*)(p + (long)g*128 + e0);
  f32x4 pv1 = *(const f32x4*)(p + (long)g*128 + e0 + 4);
  float acc[8];
  for(int r=0;r<4;r++){ acc[r] = pv0[r] + b_s[e0+r]; acc[4+r] = pv1[r] + b_s[e0+4+r]; }
  for(int m=0;m<16;m++){
    const float* wr = &w_s[m*128 + e0];
    for(int r=0;r<8;r++) acc[r] += c[m]*wr[r];
  }
  f32x4 s0, s1;
  for(int r=0;r<4;r++){ s0[r] = acc[r]; s1[r] = acc[4+r]; }
  *(f32x4*)(p1 + (long)g*128 + e0)     = s0;
  *(f32x4*)(p1 + (long)g*128 + e0 + 4) = s1;
}

// ---------------- K7a: tt = LN(p1,en2)@t_W + t_b  PURE FP32, two-pass LN ----------------
__global__ __launch_bounds__(256) void k7a_tt(const float* __restrict__ p1,
                                              const float* __restrict__ en2s,
                                              const float* __restrict__ en2b,
                                              const float* __restrict__ tW,
                                              const float* __restrict__ tb,
                                              const int* __restrict__ am,
                                              float* __restrict__ a_part,
                                              float* __restrict__ bs_part){
  __shared__ __align__(16) float WsT[16*128];
  __shared__ float sga[64][4];
  __shared__ float sgb[64][4];
  int t = threadIdx.x;
  int jjt = blockIdx.x & 31, iig = (blockIdx.x>>5) & 31, bb = blockIdx.x>>10;
  for(int r=0;r<8;r++){
    int idx = t*8 + r;                 // tW[k][m] (128 x 16)
    int k = idx>>4, mm = idx&15;
    WsT[mm*128 + k] = tW[idx];
  }
  int lr = t>>2, qt = t&3;
  int di = lr>>3, dj = lr&7;
  long g = (long)bb*65536 + (iig*8+di)*256 + (jjt*8+dj);
  const float* pr = p1 + g*128;
  f32x4 pn4[8];
  for(int c=0;c<8;c++) pn4[c] = *(const f32x4*)(pr + c*16 + qt*4);
  float s = 0.f;
  for(int c=0;c<8;c++) for(int r=0;r<4;r++) s += pn4[c][r];
  s += __shfl_xor(s,1); s += __shfl_xor(s,2);
  float m = s*(1.f/128.f);
  float sq = 0.f;
  for(int c=0;c<8;c++) for(int r=0;r<4;r++){ float d = pn4[c][r]-m; sq += d*d; }
  sq += __shfl_xor(sq,1); sq += __shfl_xor(sq,2);
  float rstd = rsqrtf(sq*(1.f/128.f) + 1e-5f);
  for(int c=0;c<8;c++){
    f32x4 sv = *(const f32x4*)(en2s + c*16 + qt*4);
    f32x4 bv = *(const f32x4*)(en2b + c*16 + qt*4);
    for(int r=0;r<4;r++) pn4[c][r] = (pn4[c][r]-m)*rstd*sv[r] + bv[r];
  }
  __syncthreads();   // WsT visible
  float acc[16];
  #pragma unroll
  for(int mm=0;mm<16;mm++){
    const float* wrow = &WsT[mm*128 + qt*4];
    float a = 0.f;
    #pragma unroll
    for(int c=0;c<8;c++){
      f32x4 wv = *(const f32x4*)(wrow + c*16);
      a += pn4[c][0]*wv[0] + pn4[c][1]*wv[1] + pn4[c][2]*wv[2] + pn4[c][3]*wv[3];
    }
    acc[mm] = a;
  }
  #pragma unroll
  for(int mm=0;mm<16;mm++){
    acc[mm] += __shfl_xor(acc[mm],1);
    acc[mm] += __shfl_xor(acc[mm],2);
    acc[mm] += tb[mm];
  }
  int msk = am[(bb*256 + iig*8+di)*256 + jjt*8+dj];
  if(qt==0){      for(int r=0;r<4;r++) sga[lr][r] = msk ? sigmf(acc[r]  *acc[4+r])  : 0.f; }
  else if(qt==1){ for(int r=0;r<4;r++) sgb[lr][r] = msk ? sigmf(acc[8+r]*acc[12+r]) : 0.f; }
  __syncthreads();
  if(t < 32){
    int djr = t>>2, r = t&3;
    float sum = 0.f;
    for(int d=0;d<8;d++) sum += sga[d*8+djr][r];
    a_part[(((long)bb*32+iig)*256 + jjt*8+djr)*4 + r] = sum;
  } else if(t < 64){
    int dir = (t-32)>>2, r = t&3;
    float sum = 0.f;
    for(int d=0;d<8;d++) sum += sgb[dir*8+d][r];
    bs_part[(((long)bb*32+jjt)*256 + iig*8+dir)*4 + r] = sum;
  }
}

// ---------------- K6b: reduce partials; A2 = a@t6_W ; Bs2 = bsum@t6_W + t6_b ----------------
__global__ __launch_bounds__(128) void k6b(const float* __restrict__ a_part,
                                           const float* __restrict__ bs_part,
                                           const float* __restrict__ t6W,
                                           const float* __restrict__ t6b,
                                           float* __restrict__ A2, float* __restrict__ Bs2){
  int d = blockIdx.x;          // bb*256 + row
  int bb = d>>8, rw = d&255;
  int e = threadIdx.x;
  __shared__ float as[4], bsr[4];
  if(e < 4){
    float s = 0.f;
    for(int g=0;g<32;g++) s += a_part[(((long)bb*32+g)*256 + rw)*4 + e];
    as[e] = s;
  } else if(e < 8){
    int r = e-4;
    float s = 0.f;
    for(int g=0;g<32;g++) s += bs_part[(((long)bb*32+g)*256 + rw)*4 + r];
    bsr[r] = s;
  }
  __syncthreads();
  float sa = 0.f, sb = 0.f;
  for(int h=0;h<4;h++){
    float wv = t6W[h*128+e];
    sa += as[h]*wv;
    sb += bsr[h]*wv;
  }
  A2[d*128+e]  = sa;
  Bs2[d*128+e] = sb + t6b[e];
}

// ---------------- K7b: t5 = LN(p1,en2)@t5_W + t5_b ; p2 = p1 + sigmoid(t5*(A2+Bs2)) ----------------
// PURE FP32, register LN (two-pass); t5WT staged via LDS in 8 tiles of 16 rows.
__global__ __launch_bounds__(256) void k7b_p2(float* __restrict__ dp,
                                              const float* __restrict__ en2s,
                                              const float* __restrict__ en2b,
                                              const float* __restrict__ t5WT,
                                              const float* __restrict__ t5b,
                                              const float* __restrict__ A2,
                                              const float* __restrict__ Bs2,
                                              const int* __restrict__ am){
  __shared__ __align__(16) float Ws[16*128];
  int t = threadIdx.x;
  int lr = t>>2, qt = t&3;
  long g = (long)blockIdx.x*64 + lr;
  int bb = (int)(g>>16), ii = ((int)(g>>8))&255, jj = (int)g&255;
  float* pr = dp + g*128;
  f32x4 praw[8], pn4[8];
  #pragma unroll
  for(int c=0;c<8;c++){ praw[c] = *(const f32x4*)(pr + c*16 + qt*4); pn4[c] = praw[c]; }
  float s = 0.f;
  #pragma unroll
  for(int c=0;c<8;c++) for(int r=0;r<4;r++) s += pn4[c][r];
  s += __shfl_xor(s,1); s += __shfl_xor(s,2);
  float m = s*(1.f/128.f);
  float sq = 0.f;
  #pragma unroll
  for(int c=0;c<8;c++) for(int r=0;r<4;r++){ float d = pn4[c][r]-m; sq += d*d; }
  sq += __shfl_xor(sq,1); sq += __shfl_xor(sq,2);
  float rstd = rsqrtf(sq*(1.f/128.f) + 1e-5f);
  #pragma unroll
  for(int c=0;c<8;c++){
    f32x4 sv = *(const f32x4*)(en2s + c*16 + qt*4);
    f32x4 bv = *(const f32x4*)(en2b + c*16 + qt*4);
    for(int r=0;r<4;r++) pn4[c][r] = (pn4[c][r]-m)*rstd*sv[r] + bv[r];
  }
  int msk = am[(bb*256+ii)*256 + jj];
  const float* A2p = A2 + (bb*256+jj)*128;
  const float* Bsp = Bs2 + (bb*256+ii)*128;
  for(int mg=0;mg<8;mg++){
    __syncthreads();
    for(int r2=0;r2<8;r2++) Ws[t*8+r2] = t5WT[mg*2048 + t*8 + r2];
    __syncthreads();
    float acc[16];
    #pragma unroll
    for(int mm=0;mm<16;mm++){
      const float* wrow = &Ws[mm*128 + qt*4];
      float a = 0.f;
      #pragma unroll
      for(int c=0;c<8;c++){
        f32x4 wv = *(const f32x4*)(wrow + c*16);
        a += pn4[c][0]*wv[0] + pn4[c][1]*wv[1] + pn4[c][2]*wv[2] + pn4[c][3]*wv[3];
      }
      acc[mm] = a;
    }
    #pragma unroll
    for(int mm=0;mm<16;mm++){ acc[mm] += __shfl_xor(acc[mm],1); acc[mm] += __shfl_xor(acc[mm],2); }
    float tv[4];
    if(qt==0){      tv[0]=acc[0];  tv[1]=acc[1];  tv[2]=acc[2];  tv[3]=acc[3];  }
    else if(qt==1){ tv[0]=acc[4];  tv[1]=acc[5];  tv[2]=acc[6];  tv[3]=acc[7];  }
    else if(qt==2){ tv[0]=acc[8];  tv[1]=acc[9];  tv[2]=acc[10]; tv[3]=acc[11]; }
    else{           tv[0]=acc[12]; tv[1]=acc[13]; tv[2]=acc[14]; tv[3]=acc[15]; }
    int e0 = mg*16 + qt*4;
    f32x4 b4 = *(const f32x4*)(t5b + e0);
    f32x4 ov;
    #pragma unroll
    for(int r=0;r<4;r++){
      float sg = 0.f;
      if(msk){
        float t56 = (tv[r] + b4[r]) * (A2p[e0+r] + Bsp[e0+r]);
        sg = sigmf(t56);
      }
      ov[r] = praw[mg][r] + sg;
    }
    *(f32x4*)(pr + e0) = ov;
  }
}

// ---------------- K8: p3 = p2 + gelu(LN(p2,en3)@effn1+b)@effn2 + b ----------------
// 16 rows/block; GEMM1 3-term; h stored bf16 hi/lo; GEMM2 3-term; two-pass LN.
__global__ __launch_bounds__(256) void k8_effn(float* __restrict__ dp,
                                               const float* __restrict__ en3s,
                                               const float* __restrict__ en3b,
                                               const unsigned short* __restrict__ W1h,
                                               const unsigned short* __restrict__ W1l,
                                               const float* __restrict__ b1,
                                               const unsigned short* __restrict__ W2h,
                                               const unsigned short* __restrict__ W2l,
                                               const float* __restrict__ b2){
  __shared__ __align__(16) unsigned short pn3h[16*136];
  __shared__ __align__(16) unsigned short pn3l[16*136];
  __shared__ __align__(16) unsigned short hTh[16*520];
  __shared__ __align__(16) unsigned short hTl[16*520];
  int t = threadIdx.x;
  long base = (long)blockIdx.x*16;
  { // phase A: LN(p2, en3) -> pn3 hi/lo (16 rows x 16 lanes, 8 ch/lane), two-pass
    int lr = t>>4, oct = t&15, e0 = oct*8;
    const float* pr = dp + (base+lr)*128 + e0;
    float v[8];
    for(int c=0;c<2;c++){ f32x4 u = *(const f32x4*)(pr + c*4); for(int r=0;r<4;r++) v[c*4+r] = u[r]; }
    float s = 0.f;
    for(int k=0;k<8;k++) s += v[k];
    s += __shfl_xor(s,1); s += __shfl_xor(s,2); s += __shfl_xor(s,4); s += __shfl_xor(s,8);
    float m = s*(1.f/128.f);
    float sq = 0.f;
    for(int k=0;k<8;k++){ float d = v[k]-m; sq += d*d; }
    sq += __shfl_xor(sq,1); sq += __shfl_xor(sq,2); sq += __shfl_xor(sq,4); sq += __shfl_xor(sq,8);
    float rstd = rsqrtf(sq*(1.f/128.f) + 1e-5f);
    for(int c=0;c<2;c++){
      f32x4 sv = *(const f32x4*)(en3s + e0 + c*4), bv = *(const f32x4*)(en3b + e0 + c*4);
      us4 vh, vl;
      for(int r=0;r<4;r++){
        float val = (v[c*4+r]-m)*rstd*sv[r] + bv[r];
        unsigned short h = f2b(val);
        vh[r] = h; vl[r] = f2b(val - b2f(h));
      }
      *(us4*)&pn3h[lr*136 + e0 + c*4] = vh;
      *(us4*)&pn3l[lr*136 + e0 + c*4] = vl;
    }
  }
  __syncthreads();
  int w = t>>6, lane = t&63, l15 = lane&15, q = lane>>4;
  { // GEMM1: h = gelu(pn3 @ W1 + b1), 3-term; store hi/lo
    s16x8 bh[4], bl[4];
    for(int kt=0;kt<4;kt++){
      bh[kt] = *(const s16x8*)&pn3h[l15*136 + kt*32 + q*8];
      bl[kt] = *(const s16x8*)&pn3l[l15*136 + kt*32 + q*8];
    }
    for(int mtl=0;mtl<8;mtl++){
      int mtg = w*8 + mtl;
      f32x4 acc = (f32x4){0.f,0.f,0.f,0.f};
      for(int kt=0;kt<4;kt++){
        s16x8 ah = *(const s16x8*)(W1h + ((mtg*4+kt)*64 + lane)*8);
        s16x8 al = *(const s16x8*)(W1l + ((mtg*4+kt)*64 + lane)*8);
        acc = MFMA(ah, bh[kt], acc);
        acc = MFMA(ah, bl[kt], acc);
        acc = MFMA(al, bh[kt], acc);
      }
      int col0 = mtg*16 + q*4;
      f32x4 bb = *(const f32x4*)(b1 + col0);
      us4 hv, lv;
      for(int r=0;r<4;r++){
        float gv = geluf(acc[r] + bb[r]);
        unsigned short h = f2b(gv);
        hv[r] = h; lv[r] = f2b(gv - b2f(h));
      }
      *(us4*)&hTh[l15*520 + col0] = hv;
      *(us4*)&hTl[l15*520 + col0] = lv;
    }
  }
  __syncthreads();
  { // GEMM2: out = p2 + h @ W2 + b2, 3-term
    f32x4 acc2[2];
    acc2[0] = (f32x4){0.f,0.f,0.f,0.f}; acc2[1] = acc2[0];
    for(int kt=0;kt<16;kt++){
      s16x8 bh = *(const s16x8*)&hTh[l15*520 + kt*32 + q*8];
      s16x8 bl = *(const s16x8*)&hTl[l15*520 + kt*32 + q*8];
      for(int mtl=0;mtl<2;mtl++){
        int m2 = w*2 + mtl;
        s16x8 ah = *(const s16x8*)(W2h + ((m2*16+kt)*64 + lane)*8);
        s16x8 al = *(const s16x8*)(W2l + ((m2*16+kt)*64 + lane)*8);
        acc2[mtl] = MFMA(ah, bh, acc2[mtl]);
        acc2[mtl] = MFMA(ah, bl, acc2[mtl]);
        acc2[mtl] = MFMA(al, bh, acc2[mtl]);
      }
    }
    for(int mtl=0;mtl<2;mtl++){
      int m2 = w*2 + mtl;
      int col0 = m2*16 + q*4;
      f32x4 bb = *(const f32x4*)(b2 + col0);
      long g = base + l15;
      f32x4 p2v = *(const f32x4*)(dp + g*128 + col0);
      f32x4 ov;
      for(int r=0;r<4;r++) ov[r] = p2v[r] + acc2[mtl][r] + bb[r];
      *(f32x4*)(dp + g*128 + col0) = ov;
    }
  }
}

extern "C" void kernel_launch(void* const* d_in, const int* in_sizes, int n_in,
                              void* d_out, int out_size, void* d_ws, size_t ws_size,
                              hipStream_t stream) {
  const float* x      = (const float*)d_in[0];
  const float* p      = (const float*)d_in[1];
  const int*   am     = (const int*)d_in[2];
  const float* nffn1W = (const float*)d_in[7];
  const float* nffn1b = (const float*)d_in[8];
  const float* nffn2W = (const float*)d_in[9];
  const float* nffn2b = (const float*)d_in[10];
  const float* o12W   = (const float*)d_in[11];
  const float* o12b   = (const float*)d_in[12];
  const float* o3W    = (const float*)d_in[13];
  const float* o3b    = (const float*)d_in[14];
  const float* tW     = (const float*)d_in[15];
  const float* tb     = (const float*)d_in[16];
  const float* t5W    = (const float*)d_in[17];
  const float* t5b    = (const float*)d_in[18];
  const float* t6W    = (const float*)d_in[19];
  const float* t6b    = (const float*)d_in[20];
  const float* e1W    = (const float*)d_in[21];
  const float* e1b    = (const float*)d_in[22];
  const float* e2W    = (const float*)d_in[23];
  const float* e2b    = (const float*)d_in[24];
  const float* n2s    = (const float*)d_in[27];
  const float* n2b    = (const float*)d_in[28];
  const float* en1s   = (const float*)d_in[29];
  const float* en1b   = (const float*)d_in[30];
  const float* en2s   = (const float*)d_in[31];
  const float* en2b   = (const float*)d_in[32];
  const float* en3s   = (const float*)d_in[33];
  const float* en3b   = (const float*)d_in[34];

  float* ox  = (float*)d_out;            // x out: 262144 f32
  float* opx = (float*)d_out + 262144;   // p out: 16777216 f32

  // Persistent workspace: first 1.65 MB of d_ws, zeroed at launch start.
  char* ws = (char*)d_ws;
  float* o1w    = (float*)(ws + 0);        // -> 8192
  float* o2w    = (float*)(ws + 8192);     // -> 16384
  float* A2     = (float*)(ws + 16384);    // -> 278528
  float* Bs2    = (float*)(ws + 278528);   // -> 540672
  float* t5WT   = (float*)(ws + 540672);   // -> 606208
  unsigned short* W1h  = (unsigned short*)(ws + 606208);   // -> 737280
  unsigned short* W1l  = (unsigned short*)(ws + 737280);   // -> 868352
  unsigned short* W2h  = (unsigned short*)(ws + 868352);   // -> 999424
  unsigned short* W2l  = (unsigned short*)(ws + 999424);   // -> 1130496
  float* a_part  = (float*)(ws + 1130496); // -> 1392640
  float* bs_part = (float*)(ws + 1392640); // -> 1654784

  // fp32 x-path scratch in the dead head of the p-output region (fully
  // overwritten by k5 before any of opx is consumed as output).
  char* sc = (char*)opx;
  float* xnf = (float*)(sc + 0);           // 512*512 f32 = 1 MB
  float* hf  = (float*)(sc + 1048576);     // 512*2048 f32 = 4 MB (ends 5242880)

  k_zero<<<404, 256, 0, stream>>>((float*)ws);   // 404*256*16B = 1654784 B

  k_repackT<<<64,  256, 0, stream>>>(t5W, t5WT);
  k_repack2<<<32,  256, 0, stream>>>(e1W, W1h, W1l, 512, 2, 8192);
  k_repack2<<<32,  256, 0, stream>>>(e2W, W2h, W2l, 128, 4, 8192);

  k1_ln<<<512, 256, 0, stream>>>(x, n2s, n2b, xnf);
  k2_f32<<<dim3(16,32), 256, 0, stream>>>(xnf, nffn1W, nffn1b, hf);
  k3_f32<<<dim3(4,32),  256, 0, stream>>>(hf, nffn2W, nffn2b, x, ox);
  k4_o12<<<512, 256, 0, stream>>>(ox, en1s, en1b, o12W, o12b, o1w, o2w);

  k5_p1<<<8192, 256, 0, stream>>>(p, o3W, o3b, o1w, o2w, opx);
  k7a_tt<<<2048, 256, 0, stream>>>(opx, en2s, en2b, tW, tb, am, a_part, bs_part);
  k6b<<<512, 128, 0, stream>>>(a_part, bs_part, t6W, t6b, A2, Bs2);
  k7b_p2<<<2048, 256, 0, stream>>>(opx, en2s, en2b, t5WT, t5b, A2, Bs2, am);
  k8_effn<<<8192, 256, 0, stream>>>(opx, en3s, en3b, W1h, W1l, e1b, W2h, W2l, e2b);
}

// Round 10
// 638.577 us; speedup vs baseline: 1.6974x; 1.6974x over previous
//
#include <hip/hip_runtime.h>
#include <hip/hip_bf16.h>

typedef __attribute__((ext_vector_type(8))) short s16x8;
typedef __attribute__((ext_vector_type(4))) float f32x4;
typedef __attribute__((ext_vector_type(4))) unsigned short us4;

#define DI __device__ __forceinline__

DI float b2f(unsigned short u){ union{float f; unsigned int i;} v; v.i = ((unsigned int)u)<<16; return v.f; }
DI unsigned short f2b(float f){ union{float f; unsigned int i;} v; v.f = f; unsigned int r = v.i + 0x7FFF + ((v.i>>16)&1u); return (unsigned short)(r>>16); }
DI float geluf(float x){ return 0.5f*x*(1.f + erff(x*0.70710678118654752f)); }
DI float sigmf(float x){ return 1.f/(1.f + expf(-x)); }

#define MFMA(a,b,c) __builtin_amdgcn_mfma_f32_16x16x32_bf16((a),(b),(c),0,0,0)

// ---------------- zero workspace (determinism armor) ----------------
__global__ __launch_bounds__(256) void k_zero(float* __restrict__ w){
  int idx = blockIdx.x*256 + threadIdx.x;
  *(f32x4*)(w + (long)idx*4) = (f32x4){0.f,0.f,0.f,0.f};
}

// ---------------- hi/lo split repack (K x M row-major fp32 -> bf16 MFMA A-frag layout) ----------------
__global__ __launch_bounds__(256) void k_repack2(const float* __restrict__ W,
                                                 unsigned short* __restrict__ oh,
                                                 unsigned short* __restrict__ ol,
                                                 int M, int ktlog2, int nthreads){
  int idx = blockIdx.x*256 + threadIdx.x;
  if(idx >= nthreads) return;
  int lane = idx & 63;
  int kt   = (idx>>6) & ((1<<ktlog2)-1);
  int mt   = idx >> (6+ktlog2);
  int k0 = kt*32 + (lane>>4)*8;
  int m  = mt*16 + (lane&15);
  s16x8 vh, vl;
  for(int j=0;j<8;j++){
    float v = W[(k0+j)*M + m];
    unsigned short h = f2b(v);
    vh[j] = (short)h;
    vl[j] = (short)f2b(v - b2f(h));
  }
  *(s16x8*)(oh + (long)idx*8) = vh;
  *(s16x8*)(ol + (long)idx*8) = vl;
}

// ---------------- K1: xn = LN(x, n2) fp32 (two-pass) ----------------
__global__ __launch_bounds__(256) void k1_ln(const float* __restrict__ x,
                                             const float* __restrict__ s,
                                             const float* __restrict__ b,
                                             float* __restrict__ xn){
  int row = blockIdx.x, t = threadIdx.x;
  const float* xr = x + row*512;
  float v0 = xr[t], v1 = xr[t+256];
  float sum = v0+v1;
  for(int o=32;o>=1;o>>=1) sum += __shfl_down(sum,o);
  __shared__ float ls[4], lq[4];
  int w = t>>6;
  if((t&63)==0) ls[w]=sum;
  __syncthreads();
  float m = (ls[0]+ls[1]+ls[2]+ls[3])*(1.f/512.f);
  float d0 = v0-m, d1 = v1-m;
  float sq = d0*d0 + d1*d1;
  for(int o=32;o>=1;o>>=1) sq += __shfl_down(sq,o);
  if((t&63)==0) lq[w]=sq;
  __syncthreads();
  float rstd = rsqrtf((lq[0]+lq[1]+lq[2]+lq[3])*(1.f/512.f) + 1e-5f);
  xn[row*512+t]     = d0*rstd*s[t]     + b[t];
  xn[row*512+t+256] = d1*rstd*s[t+256] + b[t+256];
}

// ---------------- K2s: split-K fp32 GEMM part: part[z] = xn[:, z*256:(z+1)*256] @ W1-chunk ----------------
// grid (16, 32, 2); tile 16 rows x 128 cols; K-chunk 256
__global__ __launch_bounds__(256) void k2s(const float* __restrict__ xn,
                                           const float* __restrict__ W1,
                                           float* __restrict__ part){
  __shared__ __align__(16) float As[16*264];
  int t = threadIdx.x;
  int rowbase = blockIdx.y*16;
  int colbase = blockIdx.x*128;
  int z = blockIdx.z;
  for(int k=0;k<4;k++){
    int v4 = t + k*256;            // 0..1023
    int r = v4>>6, c4 = v4&63;
    *(f32x4*)&As[r*264 + c4*4] = *(const f32x4*)(xn + (rowbase+r)*512 + z*256 + c4*4);
  }
  __syncthreads();
  int r = t>>4, cg = t&15;
  int col0 = colbase + cg*8;
  float acc[8] = {0.f,0.f,0.f,0.f,0.f,0.f,0.f,0.f};
  #pragma unroll 4
  for(int k=0;k<256;k++){
    float a = As[r*264+k];
    f32x4 w0 = *(const f32x4*)(W1 + (long)(z*256+k)*2048 + col0);
    f32x4 w1 = *(const f32x4*)(W1 + (long)(z*256+k)*2048 + col0 + 4);
    acc[0]+=a*w0[0]; acc[1]+=a*w0[1]; acc[2]+=a*w0[2]; acc[3]+=a*w0[3];
    acc[4]+=a*w1[0]; acc[5]+=a*w1[1]; acc[6]+=a*w1[2]; acc[7]+=a*w1[3];
  }
  float* dst = part + (long)z*1048576 + (long)(rowbase+r)*2048 + col0;
  f32x4 o0, o1v;
  for(int j=0;j<4;j++){ o0[j]=acc[j]; o1v[j]=acc[4+j]; }
  *(f32x4*)dst       = o0;
  *(f32x4*)(dst + 4) = o1v;
}

// epilogue: h = gelu(part0 + part1 + b1)
__global__ __launch_bounds__(256) void k2e(const float* __restrict__ part,
                                           const float* __restrict__ b1,
                                           float* __restrict__ h){
  int i4 = blockIdx.x*256 + threadIdx.x;   // 262144 vec4s
  f32x4 a = *(const f32x4*)(part + (long)i4*4);
  f32x4 b = *(const f32x4*)(part + 1048576 + (long)i4*4);
  int col = (i4*4) & 2047;
  f32x4 bb = *(const f32x4*)(b1 + col);
  f32x4 o;
  for(int j=0;j<4;j++) o[j] = geluf(a[j] + b[j] + bb[j]);
  *(f32x4*)(h + (long)i4*4) = o;
}

// ---------------- K3s: split-K fp32 GEMM part: part[z] = h[:, z*256:(z+1)*256] @ W2-chunk ----------------
// grid (4, 32, 8); tile 16 rows x 128 cols; K-chunk 256
__global__ __launch_bounds__(256) void k3s(const float* __restrict__ h,
                                           const float* __restrict__ W2,
                                           float* __restrict__ part){
  __shared__ __align__(16) float As[16*264];
  int t = threadIdx.x;
  int rowbase = blockIdx.y*16;
  int colbase = blockIdx.x*128;
  int z = blockIdx.z;
  for(int k=0;k<4;k++){
    int v4 = t + k*256;
    int r = v4>>6, c4 = v4&63;
    *(f32x4*)&As[r*264 + c4*4] = *(const f32x4*)(h + (long)(rowbase+r)*2048 + z*256 + c4*4);
  }
  __syncthreads();
  int r = t>>4, cg = t&15;
  int col0 = colbase + cg*8;
  float acc[8] = {0.f,0.f,0.f,0.f,0.f,0.f,0.f,0.f};
  #pragma unroll 4
  for(int k=0;k<256;k++){
    float a = As[r*264+k];
    f32x4 w0 = *(const f32x4*)(W2 + (long)(z*256+k)*512 + col0);
    f32x4 w1 = *(const f32x4*)(W2 + (long)(z*256+k)*512 + col0 + 4);
    acc[0]+=a*w0[0]; acc[1]+=a*w0[1]; acc[2]+=a*w0[2]; acc[3]+=a*w0[3];
    acc[4]+=a*w1[0]; acc[5]+=a*w1[1]; acc[6]+=a*w1[2]; acc[7]+=a*w1[3];
  }
  float* dst = part + (long)z*262144 + (long)(rowbase+r)*512 + col0;
  f32x4 o0, o1v;
  for(int j=0;j<4;j++){ o0[j]=acc[j]; o1v[j]=acc[4+j]; }
  *(f32x4*)dst       = o0;
  *(f32x4*)(dst + 4) = o1v;
}

// epilogue: xout = x + sum_z part[z] + b2
__global__ __launch_bounds__(256) void k3e(const float* __restrict__ part,
                                           const float* __restrict__ b2,
                                           const float* __restrict__ x,
                                           float* __restrict__ xout){
  int i4 = blockIdx.x*256 + threadIdx.x;   // 65536 vec4s
  f32x4 s = *(const f32x4*)(part + (long)i4*4);
  for(int z=1;z<8;z++){
    f32x4 u = *(const f32x4*)(part + (long)z*262144 + (long)i4*4);
    for(int j=0;j<4;j++) s[j] += u[j];
  }
  int col = (i4*4) & 511;
  f32x4 bb = *(const f32x4*)(b2 + col);
  f32x4 xv = *(const f32x4*)(x + (long)i4*4);
  f32x4 o;
  for(int j=0;j<4;j++) o[j] = xv[j] + s[j] + bb[j];
  *(f32x4*)(xout + (long)i4*4) = o;
}

// ---------------- K4: o = LN(x_out,en1) @ o12_W + o12_b -> o1,o2 (fp32, two-pass LN) ----------------
__global__ __launch_bounds__(256) void k4_o12(const float* __restrict__ xout,
                                              const float* __restrict__ s,
                                              const float* __restrict__ b,
                                              const float* __restrict__ o12W,
                                              const float* __restrict__ o12b,
                                              float* __restrict__ o1, float* __restrict__ o2){
  int row = blockIdx.x, t = threadIdx.x;
  const float* xr = xout + row*512;
  float v0 = xr[t], v1 = xr[t+256];
  float sum = v0+v1;
  for(int o=32;o>=1;o>>=1) sum += __shfl_down(sum,o);
  __shared__ float ls[4], lq[4];
  __shared__ float red[4][8];
  int w = t>>6;
  if((t&63)==0) ls[w]=sum;
  __syncthreads();
  float m = (ls[0]+ls[1]+ls[2]+ls[3])*(1.f/512.f);
  float d0 = v0-m, d1 = v1-m;
  float sq = d0*d0 + d1*d1;
  for(int o=32;o>=1;o>>=1) sq += __shfl_down(sq,o);
  if((t&63)==0) lq[w]=sq;
  __syncthreads();
  float rstd = rsqrtf((lq[0]+lq[1]+lq[2]+lq[3])*(1.f/512.f) + 1e-5f);
  float x0 = d0*rstd*s[t]     + b[t];
  float x1 = d1*rstd*s[t+256] + b[t+256];
  f32x4 w0a = *(const f32x4*)(o12W + t*8);
  f32x4 w0b = *(const f32x4*)(o12W + t*8 + 4);
  f32x4 w1a = *(const f32x4*)(o12W + (t+256)*8), w1b = *(const f32x4*)(o12W + (t+256)*8 + 4);
  float pa[8];
  for(int r=0;r<4;r++){ pa[r]   = x0*w0a[r] + x1*w1a[r];
                        pa[4+r] = x0*w0b[r] + x1*w1b[r]; }
  for(int o=32;o>=1;o>>=1) for(int k=0;k<8;k++) pa[k] += __shfl_down(pa[k],o);
  if((t&63)==0) for(int k=0;k<8;k++) red[w][k] = pa[k];
  __syncthreads();
  if(t<8){
    float tot = red[0][t]+red[1][t]+red[2][t]+red[3][t] + o12b[t];
    if(t<4) o1[row*4+t] = tot; else o2[row*4+(t-4)] = tot;
  }
}

// ---------------- K5: p1 = p + outer(o1[i],o2[j]) @ o3_W + o3_b (fp32) ----------------
__global__ __launch_bounds__(256) void k5_p1(const float* __restrict__ p,
                                             const float* __restrict__ o3W,
                                             const float* __restrict__ o3b,
                                             const float* __restrict__ o1,
                                             const float* __restrict__ o2,
                                             float* __restrict__ p1){
  __shared__ float w_s[2048];
  __shared__ float b_s[128];
  int t = threadIdx.x;
  for(int r=0;r<8;r++) w_s[t*8+r] = o3W[t*8+r];
  if(t<128) b_s[t] = o3b[t];
  __syncthreads();
  int g = blockIdx.x*16 + (t>>4);
  int e0 = (t&15)*8;
  int bb = g>>16, ii = (g>>8)&255, jj = g&255;
  const float* o1p = o1 + (bb*256+ii)*4;
  const float* o2p = o2 + (bb*256+jj)*4;
  float c[16];
  for(int h=0;h<4;h++) for(int g2=0;g2<4;g2++) c[h*4+g2] = o1p[h]*o2p[g2];
  f32x4 pv0 = *(const f32x4*)(p + (long)g*128 + e0);
  f32x4 pv1 = *(const f32x4*)(p + (long)g*128 + e0 + 4);
  float acc[8];
  for(int r=0;r<4;r++){ acc[r] = pv0[r] + b_s[e0+r]; acc[4+r] = pv1[r] + b_s[e0+4+r]; }
  for(int m=0;m<16;m++){
    const float* wr = &w_s[m*128 + e0];
    for(int r=0;r<8;r++) acc[r] += c[m]*wr[r];
  }
  f32x4 s0, s1;
  for(int r=0;r<4;r++){ s0[r] = acc[r]; s1[r] = acc[4+r]; }
  *(f32x4*)(p1 + (long)g*128 + e0)     = s0;
  *(f32x4*)(p1 + (long)g*128 + e0 + 4) = s1;
}

// ---------------- K7a: tt = LN(p1,en2)@t_W + t_b  PURE FP32, two-pass LN ----------------
__global__ __launch_bounds__(256) void k7a_tt(const float* __restrict__ p1,
                                              const float* __restrict__ en2s,
                                              const float* __restrict__ en2b,
                                              const float* __restrict__ tW,
                                              const float* __restrict__ tb,
                                              const int* __restrict__ am,
                                              float* __restrict__ a_part,
                                              float* __restrict__ bs_part){
  __shared__ __align__(16) float WsT[16*128];
  __shared__ float sga[64][4];
  __shared__ float sgb[64][4];
  int t = threadIdx.x;
  int jjt = blockIdx.x & 31, iig = (blockIdx.x>>5) & 31, bb = blockIdx.x>>10;
  for(int r=0;r<8;r++){
    int idx = t*8 + r;                 // tW[k][m] (128 x 16)
    int k = idx>>4, mm = idx&15;
    WsT[mm*128 + k] = tW[idx];
  }
  int lr = t>>2, qt = t&3;
  int di = lr>>3, dj = lr&7;
  long g = (long)bb*65536 + (iig*8+di)*256 + (jjt*8+dj);
  const float* pr = p1 + g*128;
  f32x4 pn4[8];
  for(int c=0;c<8;c++) pn4[c] = *(const f32x4*)(pr + c*16 + qt*4);
  float s = 0.f;
  for(int c=0;c<8;c++) for(int r=0;r<4;r++) s += pn4[c][r];
  s += __shfl_xor(s,1); s += __shfl_xor(s,2);
  float m = s*(1.f/128.f);
  float sq = 0.f;
  for(int c=0;c<8;c++) for(int r=0;r<4;r++){ float d = pn4[c][r]-m; sq += d*d; }
  sq += __shfl_xor(sq,1); sq += __shfl_xor(sq,2);
  float rstd = rsqrtf(sq*(1.f/128.f) + 1e-5f);
  for(int c=0;c<8;c++){
    f32x4 sv = *(const f32x4*)(en2s + c*16 + qt*4);
    f32x4 bv = *(const f32x4*)(en2b + c*16 + qt*4);
    for(int r=0;r<4;r++) pn4[c][r] = (pn4[c][r]-m)*rstd*sv[r] + bv[r];
  }
  __syncthreads();   // WsT visible
  float acc[16];
  #pragma unroll
  for(int mm=0;mm<16;mm++){
    const float* wrow = &WsT[mm*128 + qt*4];
    float a = 0.f;
    #pragma unroll
    for(int c=0;c<8;c++){
      f32x4 wv = *(const f32x4*)(wrow + c*16);
      a += pn4[c][0]*wv[0] + pn4[c][1]*wv[1] + pn4[c][2]*wv[2] + pn4[c][3]*wv[3];
    }
    acc[mm] = a;
  }
  #pragma unroll
  for(int mm=0;mm<16;mm++){
    acc[mm] += __shfl_xor(acc[mm],1);
    acc[mm] += __shfl_xor(acc[mm],2);
    acc[mm] += tb[mm];
  }
  int msk = am[(bb*256 + iig*8+di)*256 + jjt*8+dj];
  if(qt==0){      for(int r=0;r<4;r++) sga[lr][r] = msk ? sigmf(acc[r]  *acc[4+r])  : 0.f; }
  else if(qt==1){ for(int r=0;r<4;r++) sgb[lr][r] = msk ? sigmf(acc[8+r]*acc[12+r]) : 0.f; }
  __syncthreads();
  if(t < 32){
    int djr = t>>2, r = t&3;
    float sum = 0.f;
    for(int d=0;d<8;d++) sum += sga[d*8+djr][r];
    a_part[(((long)bb*32+iig)*256 + jjt*8+djr)*4 + r] = sum;
  } else if(t < 64){
    int dir = (t-32)>>2, r = t&3;
    float sum = 0.f;
    for(int d=0;d<8;d++) sum += sgb[dir*8+d][r];
    bs_part[(((long)bb*32+jjt)*256 + iig*8+dir)*4 + r] = sum;
  }
}

// ---------------- K6b: reduce partials; A2 = a@t6_W ; Bs2 = bsum@t6_W + t6_b ----------------
__global__ __launch_bounds__(128) void k6b(const float* __restrict__ a_part,
                                           const float* __restrict__ bs_part,
                                           const float* __restrict__ t6W,
                                           const float* __restrict__ t6b,
                                           float* __restrict__ A2, float* __restrict__ Bs2){
  int d = blockIdx.x;          // bb*256 + row
  int bb = d>>8, rw = d&255;
  int e = threadIdx.x;
  __shared__ float as[4], bsr[4];
  if(e < 4){
    float s = 0.f;
    for(int g=0;g<32;g++) s += a_part[(((long)bb*32+g)*256 + rw)*4 + e];
    as[e] = s;
  } else if(e < 8){
    int r = e-4;
    float s = 0.f;
    for(int g=0;g<32;g++) s += bs_part[(((long)bb*32+g)*256 + rw)*4 + r];
    bsr[r] = s;
  }
  __syncthreads();
  float sa = 0.f, sb = 0.f;
  for(int h=0;h<4;h++){
    float wv = t6W[h*128+e];
    sa += as[h]*wv;
    sb += bsr[h]*wv;
  }
  A2[d*128+e]  = sa;
  Bs2[d*128+e] = sb + t6b[e];
}

// ---------------- LN stage: 64 rows of 128 (fp32 src) -> bf16 hi/lo LDS tiles ----------------
DI void ln_stage64(const float* __restrict__ psrc,
                   const float* __restrict__ s2,
                   const float* __restrict__ b2,
                   unsigned short* pnh, unsigned short* pnl, int t){
  int lr = t>>2, qt = t&3, e0 = qt*32;
  const float* pr = psrc + lr*128 + e0;
  float v[32];
  for(int c=0;c<8;c++){ f32x4 u = *(const f32x4*)(pr + c*4); for(int r=0;r<4;r++) v[c*4+r] = u[r]; }
  float s = 0.f;
  for(int k=0;k<32;k++) s += v[k];
  s += __shfl_xor(s,1); s += __shfl_xor(s,2);
  float m = s*(1.f/128.f);
  float sq = 0.f;
  for(int k=0;k<32;k++){ float d = v[k]-m; sq += d*d; }
  sq += __shfl_xor(sq,1); sq += __shfl_xor(sq,2);
  float rstd = rsqrtf(sq*(1.f/128.f) + 1e-5f);
  for(int c=0;c<8;c++){
    f32x4 sv = *(const f32x4*)(s2 + e0 + c*4), bv = *(const f32x4*)(b2 + e0 + c*4);
    us4 vh, vl;
    for(int r=0;r<4;r++){
      float val = (v[c*4+r]-m)*rstd*sv[r] + bv[r];
      unsigned short h = f2b(val);
      vh[r] = h; vl[r] = f2b(val - b2f(h));
    }
    *(us4*)&pnh[lr*136 + e0 + c*4] = vh;
    *(us4*)&pnl[lr*136 + e0 + c*4] = vl;
  }
}

// ---------------- K7b: t5 = LN(p1,en2)@t5_W + t5_b (3-term MFMA) ; p2 = p1 + sigmoid(...) ----------------
__global__ __launch_bounds__(256) void k7b_p2(float* __restrict__ dp,
                                              const float* __restrict__ en2s,
                                              const float* __restrict__ en2b,
                                              const unsigned short* __restrict__ t5Wh,
                                              const unsigned short* __restrict__ t5Wl,
                                              const float* __restrict__ t5b,
                                              const float* __restrict__ A2,
                                              const float* __restrict__ Bs2,
                                              const int* __restrict__ am){
  __shared__ __align__(16) unsigned short pnh[64*136];
  __shared__ __align__(16) unsigned short pnl[64*136];
  int t = threadIdx.x;
  long gbase = (long)blockIdx.x*64;
  ln_stage64(dp + gbase*128, en2s, en2b, pnh, pnl, t);
  __syncthreads();
  int w = t>>6, lane = t&63, l15 = lane&15, q = lane>>4;
  for(int mtl=0;mtl<2;mtl++){
    int mtg = w*2 + mtl;
    s16x8 afh[4], afl[4];
    for(int kt=0;kt<4;kt++){
      int wi = ((mtg*4+kt)*64 + lane)*8;
      afh[kt] = *(const s16x8*)(t5Wh + wi);
      afl[kt] = *(const s16x8*)(t5Wl + wi);
    }
    int e0 = mtg*16 + q*4;
    f32x4 t5b4 = *(const f32x4*)(t5b + e0);
    for(int nt=0;nt<4;nt++){
      f32x4 acc = (f32x4){0.f,0.f,0.f,0.f};
      for(int kt=0;kt<4;kt++){
        s16x8 bh = *(const s16x8*)&pnh[(nt*16+l15)*136 + kt*32 + q*8];
        s16x8 bl = *(const s16x8*)&pnl[(nt*16+l15)*136 + kt*32 + q*8];
        acc = MFMA(afh[kt], bh, acc);
        acc = MFMA(afh[kt], bl, acc);
        acc = MFMA(afl[kt], bh, acc);
      }
      long g = gbase + nt*16 + l15;
      int bb = (int)(g>>16), ii = ((int)(g>>8))&255, jj = (int)g&255;
      int msk = am[(bb*256+ii)*256 + jj];
      const float* A2p = A2 + (bb*256+jj)*128 + e0;
      const float* Bsp = Bs2 + (bb*256+ii)*128 + e0;
      f32x4 p1v = *(const f32x4*)(dp + g*128 + e0);
      f32x4 ov;
      for(int r=0;r<4;r++){
        float sg = 0.f;
        if(msk){
          float t56 = (acc[r] + t5b4[r]) * (A2p[r] + Bsp[r]);
          sg = sigmf(t56);
        }
        ov[r] = p1v[r] + sg;
      }
      *(f32x4*)(dp + g*128 + e0) = ov;
    }
  }
}

// ---------------- K8: p3 = p2 + gelu(LN(p2,en3)@effn1+b)@effn2 + b ----------------
// 16 rows/block; GEMM1 3-term; h stored bf16 hi/lo; GEMM2 3-term; two-pass LN.
__global__ __launch_bounds__(256) void k8_effn(float* __restrict__ dp,
                                               const float* __restrict__ en3s,
                                               const float* __restrict__ en3b,
                                               const unsigned short* __restrict__ W1h,
                                               const unsigned short* __restrict__ W1l,
                                               const float* __restrict__ b1,
                                               const unsigned short* __restrict__ W2h,
                                               const unsigned short* __restrict__ W2l,
                                               const float* __restrict__ b2){
  __shared__ __align__(16) unsigned short pn3h[16*136];
  __shared__ __align__(16) unsigned short pn3l[16*136];
  __shared__ __align__(16) unsigned short hTh[16*520];
  __shared__ __align__(16) unsigned short hTl[16*520];
  int t = threadIdx.x;
  long base = (long)blockIdx.x*16;
  { // phase A: LN(p2, en3) -> pn3 hi/lo (16 rows x 16 lanes, 8 ch/lane), two-pass
    int lr = t>>4, oct = t&15, e0 = oct*8;
    const float* pr = dp + (base+lr)*128 + e0;
    float v[8];
    for(int c=0;c<2;c++){ f32x4 u = *(const f32x4*)(pr + c*4); for(int r=0;r<4;r++) v[c*4+r] = u[r]; }
    float s = 0.f;
    for(int k=0;k<8;k++) s += v[k];
    s += __shfl_xor(s,1); s += __shfl_xor(s,2); s += __shfl_xor(s,4); s += __shfl_xor(s,8);
    float m = s*(1.f/128.f);
    float sq = 0.f;
    for(int k=0;k<8;k++){ float d = v[k]-m; sq += d*d; }
    sq += __shfl_xor(sq,1); sq += __shfl_xor(sq,2); sq += __shfl_xor(sq,4); sq += __shfl_xor(sq,8);
    float rstd = rsqrtf(sq*(1.f/128.f) + 1e-5f);
    for(int c=0;c<2;c++){
      f32x4 sv = *(const f32x4*)(en3s + e0 + c*4), bv = *(const f32x4*)(en3b + e0 + c*4);
      us4 vh, vl;
      for(int r=0;r<4;r++){
        float val = (v[c*4+r]-m)*rstd*sv[r] + bv[r];
        unsigned short h = f2b(val);
        vh[r] = h; vl[r] = f2b(val - b2f(h));
      }
      *(us4*)&pn3h[lr*136 + e0 + c*4] = vh;
      *(us4*)&pn3l[lr*136 + e0 + c*4] = vl;
    }
  }
  __syncthreads();
  int w = t>>6, lane = t&63, l15 = lane&15, q = lane>>4;
  { // GEMM1: h = gelu(pn3 @ W1 + b1), 3-term; store hi/lo
    s16x8 bh[4], bl[4];
    for(int kt=0;kt<4;kt++){
      bh[kt] = *(const s16x8*)&pn3h[l15*136 + kt*32 + q*8];
      bl[kt] = *(const s16x8*)&pn3l[l15*136 + kt*32 + q*8];
    }
    for(int mtl=0;mtl<8;mtl++){
      int mtg = w*8 + mtl;
      f32x4 acc = (f32x4){0.f,0.f,0.f,0.f};
      for(int kt=0;kt<4;kt++){
        s16x8 ah = *(const s16x8*)(W1h + ((mtg*4+kt)*64 + lane)*8);
        s16x8 al = *(const s16x8*)(W1l + ((mtg*4+kt)*64 + lane)*8);
        acc = MFMA(ah, bh[kt], acc);
        acc = MFMA(ah, bl[kt], acc);
        acc = MFMA(al, bh[kt], acc);
      }
      int col0 = mtg*16 + q*4;
      f32x4 bb = *(const f32x4*)(b1 + col0);
      us4 hv, lv;
      for(int r=0;r<4;r++){
        float gv = geluf(acc[r] + bb[r]);
        unsigned short h = f2b(gv);
        hv[r] = h; lv[r] = f2b(gv - b2f(h));
      }
      *(us4*)&hTh[l15*520 + col0] = hv;
      *(us4*)&hTl[l15*520 + col0] = lv;
    }
  }
  __syncthreads();
  { // GEMM2: out = p2 + h @ W2 + b2, 3-term
    f32x4 acc2[2];
    acc2[0] = (f32x4){0.f,0.f,0.f,0.f}; acc2[1] = acc2[0];
    for(int kt=0;kt<16;kt++){
      s16x8 bh = *(const s16x8*)&hTh[l15*520 + kt*32 + q*8];
      s16x8 bl = *(const s16x8*)&hTl[l15*520 + kt*32 + q*8];
      for(int mtl=0;mtl<2;mtl++){
        int m2 = w*2 + mtl;
        s16x8 ah = *(const s16x8*)(W2h + ((m2*16+kt)*64 + lane)*8);
        s16x8 al = *(const s16x8*)(W2l + ((m2*16+kt)*64 + lane)*8);
        acc2[mtl] = MFMA(ah, bh, acc2[mtl]);
        acc2[mtl] = MFMA(ah, bl, acc2[mtl]);
        acc2[mtl] = MFMA(al, bh, acc2[mtl]);
      }
    }
    for(int mtl=0;mtl<2;mtl++){
      int m2 = w*2 + mtl;
      int col0 = m2*16 + q*4;
      f32x4 bb = *(const f32x4*)(b2 + col0);
      long g = base + l15;
      f32x4 p2v = *(const f32x4*)(dp + g*128 + col0);
      f32x4 ov;
      for(int r=0;r<4;r++) ov[r] = p2v[r] + acc2[mtl][r] + bb[r];
      *(f32x4*)(dp + g*128 + col0) = ov;
    }
  }
}

extern "C" void kernel_launch(void* const* d_in, const int* in_sizes, int n_in,
                              void* d_out, int out_size, void* d_ws, size_t ws_size,
                              hipStream_t stream) {
  const float* x      = (const float*)d_in[0];
  const float* p      = (const float*)d_in[1];
  const int*   am     = (const int*)d_in[2];
  const float* nffn1W = (const float*)d_in[7];
  const float* nffn1b = (const float*)d_in[8];
  const float* nffn2W = (const float*)d_in[9];
  const float* nffn2b = (const float*)d_in[10];
  const float* o12W   = (const float*)d_in[11];
  const float* o12b   = (const float*)d_in[12];
  const float* o3W    = (const float*)d_in[13];
  const float* o3b    = (const float*)d_in[14];
  const float* tW     = (const float*)d_in[15];
  const float* tb     = (const float*)d_in[16];
  const float* t5W    = (const float*)d_in[17];
  const float* t5b    = (const float*)d_in[18];
  const float* t6W    = (const float*)d_in[19];
  const float* t6b    = (const float*)d_in[20];
  const float* e1W    = (const float*)d_in[21];
  const float* e1b    = (const float*)d_in[22];
  const float* e2W    = (const float*)d_in[23];
  const float* e2b    = (const float*)d_in[24];
  const float* n2s    = (const float*)d_in[27];
  const float* n2b    = (const float*)d_in[28];
  const float* en1s   = (const float*)d_in[29];
  const float* en1b   = (const float*)d_in[30];
  const float* en2s   = (const float*)d_in[31];
  const float* en2b   = (const float*)d_in[32];
  const float* en3s   = (const float*)d_in[33];
  const float* en3b   = (const float*)d_in[34];

  float* ox  = (float*)d_out;            // x out: 262144 f32
  float* opx = (float*)d_out + 262144;   // p out: 16777216 f32

  // Persistent workspace: first 1.65 MB of d_ws, zeroed at launch start.
  char* ws = (char*)d_ws;
  float* o1w    = (float*)(ws + 0);        // -> 8192
  float* o2w    = (float*)(ws + 8192);     // -> 16384
  float* A2     = (float*)(ws + 16384);    // -> 278528
  float* Bs2    = (float*)(ws + 278528);   // -> 540672
  unsigned short* t5Wh = (unsigned short*)(ws + 540672);   // -> 573440
  unsigned short* t5Wl = (unsigned short*)(ws + 573440);   // -> 606208
  unsigned short* W1h  = (unsigned short*)(ws + 606208);   // -> 737280
  unsigned short* W1l  = (unsigned short*)(ws + 737280);   // -> 868352
  unsigned short* W2h  = (unsigned short*)(ws + 868352);   // -> 999424
  unsigned short* W2l  = (unsigned short*)(ws + 999424);   // -> 1130496
  float* a_part  = (float*)(ws + 1130496); // -> 1392640
  float* bs_part = (float*)(ws + 1392640); // -> 1654784

  // fp32 x-path scratch in the dead head of the p-output region (fully
  // overwritten by k5 before any of opx is consumed as output).
  char* sc = (char*)opx;
  float* xnf    = (float*)(sc + 0);         // 1 MB
  float* hf     = (float*)(sc + 1048576);   // 4 MB -> 5242880
  float* gpart  = (float*)(sc + 5242880);   // 8 MB (k2 partials 2x4MB, then k3 partials 8x1MB) -> 13631488

  k_zero<<<404, 256, 0, stream>>>((float*)ws);   // 404*256*16B = 1654784 B

  k_repack2<<<8,   256, 0, stream>>>(t5W, t5Wh, t5Wl, 128, 2, 2048);
  k_repack2<<<32,  256, 0, stream>>>(e1W, W1h, W1l, 512, 2, 8192);
  k_repack2<<<32,  256, 0, stream>>>(e2W, W2h, W2l, 128, 4, 8192);

  k1_ln<<<512, 256, 0, stream>>>(x, n2s, n2b, xnf);
  k2s<<<dim3(16,32,2), 256, 0, stream>>>(xnf, nffn1W, gpart);
  k2e<<<1024, 256, 0, stream>>>(gpart, nffn1b, hf);
  k3s<<<dim3(4,32,8), 256, 0, stream>>>(hf, nffn2W, gpart);
  k3e<<<256, 256, 0, stream>>>(gpart, nffn2b, x, ox);
  k4_o12<<<512, 256, 0, stream>>>(ox, en1s, en1b, o12W, o12b, o1w, o2w);

  k5_p1<<<8192, 256, 0, stream>>>(p, o3W, o3b, o1w, o2w, opx);
  k7a_tt<<<2048, 256, 0, stream>>>(opx, en2s, en2b, tW, tb, am, a_part, bs_part);
  k6b<<<512, 128, 0, stream>>>(a_part, bs_part, t6W, t6b, A2, Bs2);
  k7b_p2<<<2048, 256, 0, stream>>>(opx, en2s, en2b, t5Wh, t5Wl, t5b, A2, Bs2, am);
  k8_effn<<<8192, 256, 0, stream>>>(opx, en3s, en3b, W1h, W1l, e1b, W2h, W2l, e2b);
}

// Round 11
// 583.583 us; speedup vs baseline: 1.8574x; 1.0942x over previous
//
#include <hip/hip_runtime.h>
#include <hip/hip_bf16.h>

typedef __attribute__((ext_vector_type(8))) short s16x8;
typedef __attribute__((ext_vector_type(4))) float f32x4;
typedef __attribute__((ext_vector_type(4))) unsigned short us4;

#define DI __device__ __forceinline__

DI float b2f(unsigned short u){ union{float f; unsigned int i;} v; v.i = ((unsigned int)u)<<16; return v.f; }
DI unsigned short f2b(float f){ union{float f; unsigned int i;} v; v.f = f; unsigned int r = v.i + 0x7FFF + ((v.i>>16)&1u); return (unsigned short)(r>>16); }
DI float geluf(float x){ return 0.5f*x*(1.f + erff(x*0.70710678118654752f)); }
DI float sigmf(float x){ return 1.f/(1.f + expf(-x)); }

#define MFMA(a,b,c) __builtin_amdgcn_mfma_f32_16x16x32_bf16((a),(b),(c),0,0,0)

// ---------------- zero workspace (determinism armor) ----------------
__global__ __launch_bounds__(256) void k_zero(float* __restrict__ w){
  int idx = blockIdx.x*256 + threadIdx.x;
  *(f32x4*)(w + (long)idx*4) = (f32x4){0.f,0.f,0.f,0.f};
}

// ---------------- hi/lo split repack (K x M row-major fp32 -> bf16 MFMA A-frag layout) ----------------
__global__ __launch_bounds__(256) void k_repack2(const float* __restrict__ W,
                                                 unsigned short* __restrict__ oh,
                                                 unsigned short* __restrict__ ol,
                                                 int M, int ktlog2, int nthreads){
  int idx = blockIdx.x*256 + threadIdx.x;
  if(idx >= nthreads) return;
  int lane = idx & 63;
  int kt   = (idx>>6) & ((1<<ktlog2)-1);
  int mt   = idx >> (6+ktlog2);
  int k0 = kt*32 + (lane>>4)*8;
  int m  = mt*16 + (lane&15);
  s16x8 vh, vl;
  for(int j=0;j<8;j++){
    float v = W[(k0+j)*M + m];
    unsigned short h = f2b(v);
    vh[j] = (short)h;
    vl[j] = (short)f2b(v - b2f(h));
  }
  *(s16x8*)(oh + (long)idx*8) = vh;
  *(s16x8*)(ol + (long)idx*8) = vl;
}

// ---------------- K1: xn = LN(x, n2) fp32 (two-pass) ----------------
__global__ __launch_bounds__(256) void k1_ln(const float* __restrict__ x,
                                             const float* __restrict__ s,
                                             const float* __restrict__ b,
                                             float* __restrict__ xn){
  int row = blockIdx.x, t = threadIdx.x;
  const float* xr = x + row*512;
  float v0 = xr[t], v1 = xr[t+256];
  float sum = v0+v1;
  for(int o=32;o>=1;o>>=1) sum += __shfl_down(sum,o);
  __shared__ float ls[4], lq[4];
  int w = t>>6;
  if((t&63)==0) ls[w]=sum;
  __syncthreads();
  float m = (ls[0]+ls[1]+ls[2]+ls[3])*(1.f/512.f);
  float d0 = v0-m, d1 = v1-m;
  float sq = d0*d0 + d1*d1;
  for(int o=32;o>=1;o>>=1) sq += __shfl_down(sq,o);
  if((t&63)==0) lq[w]=sq;
  __syncthreads();
  float rstd = rsqrtf((lq[0]+lq[1]+lq[2]+lq[3])*(1.f/512.f) + 1e-5f);
  xn[row*512+t]     = d0*rstd*s[t]     + b[t];
  xn[row*512+t+256] = d1*rstd*s[t+256] + b[t+256];
}

// ---------------- K2s: split-K fp32 GEMM part: part[z] = xn[:, z*256:(z+1)*256] @ W1-chunk ----------------
__global__ __launch_bounds__(256) void k2s(const float* __restrict__ xn,
                                           const float* __restrict__ W1,
                                           float* __restrict__ part){
  __shared__ __align__(16) float As[16*264];
  int t = threadIdx.x;
  int rowbase = blockIdx.y*16;
  int colbase = blockIdx.x*128;
  int z = blockIdx.z;
  for(int k=0;k<4;k++){
    int v4 = t + k*256;            // 0..1023
    int r = v4>>6, c4 = v4&63;
    *(f32x4*)&As[r*264 + c4*4] = *(const f32x4*)(xn + (rowbase+r)*512 + z*256 + c4*4);
  }
  __syncthreads();
  int r = t>>4, cg = t&15;
  int col0 = colbase + cg*8;
  float acc[8] = {0.f,0.f,0.f,0.f,0.f,0.f,0.f,0.f};
  #pragma unroll 4
  for(int k=0;k<256;k++){
    float a = As[r*264+k];
    f32x4 w0 = *(const f32x4*)(W1 + (long)(z*256+k)*2048 + col0);
    f32x4 w1 = *(const f32x4*)(W1 + (long)(z*256+k)*2048 + col0 + 4);
    acc[0]+=a*w0[0]; acc[1]+=a*w0[1]; acc[2]+=a*w0[2]; acc[3]+=a*w0[3];
    acc[4]+=a*w1[0]; acc[5]+=a*w1[1]; acc[6]+=a*w1[2]; acc[7]+=a*w1[3];
  }
  float* dst = part + (long)z*1048576 + (long)(rowbase+r)*2048 + col0;
  f32x4 o0, o1v;
  for(int j=0;j<4;j++){ o0[j]=acc[j]; o1v[j]=acc[4+j]; }
  *(f32x4*)dst       = o0;
  *(f32x4*)(dst + 4) = o1v;
}

// epilogue: h = gelu(part0 + part1 + b1)
__global__ __launch_bounds__(256) void k2e(const float* __restrict__ part,
                                           const float* __restrict__ b1,
                                           float* __restrict__ h){
  int i4 = blockIdx.x*256 + threadIdx.x;   // 262144 vec4s
  f32x4 a = *(const f32x4*)(part + (long)i4*4);
  f32x4 b = *(const f32x4*)(part + 1048576 + (long)i4*4);
  int col = (i4*4) & 2047;
  f32x4 bb = *(const f32x4*)(b1 + col);
  f32x4 o;
  for(int j=0;j<4;j++) o[j] = geluf(a[j] + b[j] + bb[j]);
  *(f32x4*)(h + (long)i4*4) = o;
}

// ---------------- K3s: split-K fp32 GEMM part: part[z] = h[:, z*256:(z+1)*256] @ W2-chunk ----------------
__global__ __launch_bounds__(256) void k3s(const float* __restrict__ h,
                                           const float* __restrict__ W2,
                                           float* __restrict__ part){
  __shared__ __align__(16) float As[16*264];
  int t = threadIdx.x;
  int rowbase = blockIdx.y*16;
  int colbase = blockIdx.x*128;
  int z = blockIdx.z;
  for(int k=0;k<4;k++){
    int v4 = t + k*256;
    int r = v4>>6, c4 = v4&63;
    *(f32x4*)&As[r*264 + c4*4] = *(const f32x4*)(h + (long)(rowbase+r)*2048 + z*256 + c4*4);
  }
  __syncthreads();
  int r = t>>4, cg = t&15;
  int col0 = colbase + cg*8;
  float acc[8] = {0.f,0.f,0.f,0.f,0.f,0.f,0.f,0.f};
  #pragma unroll 4
  for(int k=0;k<256;k++){
    float a = As[r*264+k];
    f32x4 w0 = *(const f32x4*)(W2 + (long)(z*256+k)*512 + col0);
    f32x4 w1 = *(const f32x4*)(W2 + (long)(z*256+k)*512 + col0 + 4);
    acc[0]+=a*w0[0]; acc[1]+=a*w0[1]; acc[2]+=a*w0[2]; acc[3]+=a*w0[3];
    acc[4]+=a*w1[0]; acc[5]+=a*w1[1]; acc[6]+=a*w1[2]; acc[7]+=a*w1[3];
  }
  float* dst = part + (long)z*262144 + (long)(rowbase+r)*512 + col0;
  f32x4 o0, o1v;
  for(int j=0;j<4;j++){ o0[j]=acc[j]; o1v[j]=acc[4+j]; }
  *(f32x4*)dst       = o0;
  *(f32x4*)(dst + 4) = o1v;
}

// epilogue: xout = x + sum_z part[z] + b2
__global__ __launch_bounds__(256) void k3e(const float* __restrict__ part,
                                           const float* __restrict__ b2,
                                           const float* __restrict__ x,
                                           float* __restrict__ xout){
  int i4 = blockIdx.x*256 + threadIdx.x;   // 65536 vec4s
  f32x4 s = *(const f32x4*)(part + (long)i4*4);
  for(int z=1;z<8;z++){
    f32x4 u = *(const f32x4*)(part + (long)z*262144 + (long)i4*4);
    for(int j=0;j<4;j++) s[j] += u[j];
  }
  int col = (i4*4) & 511;
  f32x4 bb = *(const f32x4*)(b2 + col);
  f32x4 xv = *(const f32x4*)(x + (long)i4*4);
  f32x4 o;
  for(int j=0;j<4;j++) o[j] = xv[j] + s[j] + bb[j];
  *(f32x4*)(xout + (long)i4*4) = o;
}

// ---------------- K4: o = LN(x_out,en1) @ o12_W + o12_b -> o1,o2 (fp32, two-pass LN) ----------------
__global__ __launch_bounds__(256) void k4_o12(const float* __restrict__ xout,
                                              const float* __restrict__ s,
                                              const float* __restrict__ b,
                                              const float* __restrict__ o12W,
                                              const float* __restrict__ o12b,
                                              float* __restrict__ o1, float* __restrict__ o2){
  int row = blockIdx.x, t = threadIdx.x;
  const float* xr = xout + row*512;
  float v0 = xr[t], v1 = xr[t+256];
  float sum = v0+v1;
  for(int o=32;o>=1;o>>=1) sum += __shfl_down(sum,o);
  __shared__ float ls[4], lq[4];
  __shared__ float red[4][8];
  int w = t>>6;
  if((t&63)==0) ls[w]=sum;
  __syncthreads();
  float m = (ls[0]+ls[1]+ls[2]+ls[3])*(1.f/512.f);
  float d0 = v0-m, d1 = v1-m;
  float sq = d0*d0 + d1*d1;
  for(int o=32;o>=1;o>>=1) sq += __shfl_down(sq,o);
  if((t&63)==0) lq[w]=sq;
  __syncthreads();
  float rstd = rsqrtf((lq[0]+lq[1]+lq[2]+lq[3])*(1.f/512.f) + 1e-5f);
  float x0 = d0*rstd*s[t]     + b[t];
  float x1 = d1*rstd*s[t+256] + b[t+256];
  f32x4 w0a = *(const f32x4*)(o12W + t*8);
  f32x4 w0b = *(const f32x4*)(o12W + t*8 + 4);
  f32x4 w1a = *(const f32x4*)(o12W + (t+256)*8), w1b = *(const f32x4*)(o12W + (t+256)*8 + 4);
  float pa[8];
  for(int r=0;r<4;r++){ pa[r]   = x0*w0a[r] + x1*w1a[r];
                        pa[4+r] = x0*w0b[r] + x1*w1b[r]; }
  for(int o=32;o>=1;o>>=1) for(int k=0;k<8;k++) pa[k] += __shfl_down(pa[k],o);
  if((t&63)==0) for(int k=0;k<8;k++) red[w][k] = pa[k];
  __syncthreads();
  if(t<8){
    float tot = red[0][t]+red[1][t]+red[2][t]+red[3][t] + o12b[t];
    if(t<4) o1[row*4+t] = tot; else o2[row*4+(t-4)] = tot;
  }
}

// ---------------- K5: p1 = p + outer(o1[i],o2[j]) @ o3_W + o3_b (fp32) ----------------
__global__ __launch_bounds__(256) void k5_p1(const float* __restrict__ p,
                                             const float* __restrict__ o3W,
                                             const float* __restrict__ o3b,
                                             const float* __restrict__ o1,
                                             const float* __restrict__ o2,
                                             float* __restrict__ p1){
  __shared__ float w_s[2048];
  __shared__ float b_s[128];
  int t = threadIdx.x;
  for(int r=0;r<8;r++) w_s[t*8+r] = o3W[t*8+r];
  if(t<128) b_s[t] = o3b[t];
  __syncthreads();
  int g = blockIdx.x*16 + (t>>4);
  int e0 = (t&15)*8;
  int bb = g>>16, ii = (g>>8)&255, jj = g&255;
  const float* o1p = o1 + (bb*256+ii)*4;
  const float* o2p = o2 + (bb*256+jj)*4;
  float c[16];
  for(int h=0;h<4;h++) for(int g2=0;g2<4;g2++) c[h*4+g2] = o1p[h]*o2p[g2];
  f32x4 pv0 = *(const f32x4*)(p + (long)g*128 + e0);
  f32x4 pv1 = *(const f32x4*)(p + (long)g*128 + e0 + 4);
  float acc[8];
  for(int r=0;r<4;r++){ acc[r] = pv0[r] + b_s[e0+r]; acc[4+r] = pv1[r] + b_s[e0+4+r]; }
  for(int m=0;m<16;m++){
    const float* wr = &w_s[m*128 + e0];
    for(int r=0;r<8;r++) acc[r] += c[m]*wr[r];
  }
  f32x4 s0, s1;
  for(int r=0;r<4;r++){ s0[r] = acc[r]; s1[r] = acc[4+r]; }
  *(f32x4*)(p1 + (long)g*128 + e0)     = s0;
  *(f32x4*)(p1 + (long)g*128 + e0 + 4) = s1;
}

// ---------------- K7a: tt = LN(p1,en2)@t_W + t_b  PURE FP32, two-pass LN ----------------
__global__ __launch_bounds__(256) void k7a_tt(const float* __restrict__ p1,
                                              const float* __restrict__ en2s,
                                              const float* __restrict__ en2b,
                                              const float* __restrict__ tW,
                                              const float* __restrict__ tb,
                                              const int* __restrict__ am,
                                              float* __restrict__ a_part,
                                              float* __restrict__ bs_part){
  __shared__ __align__(16) float WsT[16*128];
  __shared__ float sga[64][4];
  __shared__ float sgb[64][4];
  int t = threadIdx.x;
  int jjt = blockIdx.x & 31, iig = (blockIdx.x>>5) & 31, bb = blockIdx.x>>10;
  for(int r=0;r<8;r++){
    int idx = t*8 + r;                 // tW[k][m] (128 x 16)
    int k = idx>>4, mm = idx&15;
    WsT[mm*128 + k] = tW[idx];
  }
  int lr = t>>2, qt = t&3;
  int di = lr>>3, dj = lr&7;
  long g = (long)bb*65536 + (iig*8+di)*256 + (jjt*8+dj);
  const float* pr = p1 + g*128;
  f32x4 pn4[8];
  for(int c=0;c<8;c++) pn4[c] = *(const f32x4*)(pr + c*16 + qt*4);
  float s = 0.f;
  for(int c=0;c<8;c++) for(int r=0;r<4;r++) s += pn4[c][r];
  s += __shfl_xor(s,1); s += __shfl_xor(s,2);
  float m = s*(1.f/128.f);
  float sq = 0.f;
  for(int c=0;c<8;c++) for(int r=0;r<4;r++){ float d = pn4[c][r]-m; sq += d*d; }
  sq += __shfl_xor(sq,1); sq += __shfl_xor(sq,2);
  float rstd = rsqrtf(sq*(1.f/128.f) + 1e-5f);
  for(int c=0;c<8;c++){
    f32x4 sv = *(const f32x4*)(en2s + c*16 + qt*4);
    f32x4 bv = *(const f32x4*)(en2b + c*16 + qt*4);
    for(int r=0;r<4;r++) pn4[c][r] = (pn4[c][r]-m)*rstd*sv[r] + bv[r];
  }
  __syncthreads();   // WsT visible
  float acc[16];
  #pragma unroll
  for(int mm=0;mm<16;mm++){
    const float* wrow = &WsT[mm*128 + qt*4];
    float a = 0.f;
    #pragma unroll
    for(int c=0;c<8;c++){
      f32x4 wv = *(const f32x4*)(wrow + c*16);
      a += pn4[c][0]*wv[0] + pn4[c][1]*wv[1] + pn4[c][2]*wv[2] + pn4[c][3]*wv[3];
    }
    acc[mm] = a;
  }
  #pragma unroll
  for(int mm=0;mm<16;mm++){
    acc[mm] += __shfl_xor(acc[mm],1);
    acc[mm] += __shfl_xor(acc[mm],2);
    acc[mm] += tb[mm];
  }
  int msk = am[(bb*256 + iig*8+di)*256 + jjt*8+dj];
  if(qt==0){      for(int r=0;r<4;r++) sga[lr][r] = msk ? sigmf(acc[r]  *acc[4+r])  : 0.f; }
  else if(qt==1){ for(int r=0;r<4;r++) sgb[lr][r] = msk ? sigmf(acc[8+r]*acc[12+r]) : 0.f; }
  __syncthreads();
  if(t < 32){
    int djr = t>>2, r = t&3;
    float sum = 0.f;
    for(int d=0;d<8;d++) sum += sga[d*8+djr][r];
    a_part[(((long)bb*32+iig)*256 + jjt*8+djr)*4 + r] = sum;
  } else if(t < 64){
    int dir = (t-32)>>2, r = t&3;
    float sum = 0.f;
    for(int d=0;d<8;d++) sum += sgb[dir*8+d][r];
    bs_part[(((long)bb*32+jjt)*256 + iig*8+dir)*4 + r] = sum;
  }
}

// ---------------- K6b: reduce partials; A2 = a@t6_W ; Bs2 = bsum@t6_W + t6_b ----------------
__global__ __launch_bounds__(128) void k6b(const float* __restrict__ a_part,
                                           const float* __restrict__ bs_part,
                                           const float* __restrict__ t6W,
                                           const float* __restrict__ t6b,
                                           float* __restrict__ A2, float* __restrict__ Bs2){
  int d = blockIdx.x;          // bb*256 + row
  int bb = d>>8, rw = d&255;
  int e = threadIdx.x;
  __shared__ float as[4], bsr[4];
  if(e < 4){
    float s = 0.f;
    for(int g=0;g<32;g++) s += a_part[(((long)bb*32+g)*256 + rw)*4 + e];
    as[e] = s;
  } else if(e < 8){
    int r = e-4;
    float s = 0.f;
    for(int g=0;g<32;g++) s += bs_part[(((long)bb*32+g)*256 + rw)*4 + r];
    bsr[r] = s;
  }
  __syncthreads();
  float sa = 0.f, sb = 0.f;
  for(int h=0;h<4;h++){
    float wv = t6W[h*128+e];
    sa += as[h]*wv;
    sb += bsr[h]*wv;
  }
  A2[d*128+e]  = sa;
  Bs2[d*128+e] = sb + t6b[e];
}

// ---------------- LN stage: 64 rows of 128 (fp32 src) -> bf16 hi/lo LDS tiles ----------------
DI void ln_stage64(const float* __restrict__ psrc,
                   const float* __restrict__ s2,
                   const float* __restrict__ b2,
                   unsigned short* pnh, unsigned short* pnl, int t){
  int lr = t>>2, qt = t&3, e0 = qt*32;
  const float* pr = psrc + lr*128 + e0;
  float v[32];
  for(int c=0;c<8;c++){ f32x4 u = *(const f32x4*)(pr + c*4); for(int r=0;r<4;r++) v[c*4+r] = u[r]; }
  float s = 0.f;
  for(int k=0;k<32;k++) s += v[k];
  s += __shfl_xor(s,1); s += __shfl_xor(s,2);
  float m = s*(1.f/128.f);
  float sq = 0.f;
  for(int k=0;k<32;k++){ float d = v[k]-m; sq += d*d; }
  sq += __shfl_xor(sq,1); sq += __shfl_xor(sq,2);
  float rstd = rsqrtf(sq*(1.f/128.f) + 1e-5f);
  for(int c=0;c<8;c++){
    f32x4 sv = *(const f32x4*)(s2 + e0 + c*4), bv = *(const f32x4*)(b2 + e0 + c*4);
    us4 vh, vl;
    for(int r=0;r<4;r++){
      float val = (v[c*4+r]-m)*rstd*sv[r] + bv[r];
      unsigned short h = f2b(val);
      vh[r] = h; vl[r] = f2b(val - b2f(h));
    }
    *(us4*)&pnh[lr*136 + e0 + c*4] = vh;
    *(us4*)&pnl[lr*136 + e0 + c*4] = vl;
  }
}

// ---------------- K7b: t5 = LN(p1,en2)@t5_W + t5_b (3-term MFMA) ; p2 = p1 + sigmoid(...) ----------------
__global__ __launch_bounds__(256) void k7b_p2(float* __restrict__ dp,
                                              const float* __restrict__ en2s,
                                              const float* __restrict__ en2b,
                                              const unsigned short* __restrict__ t5Wh,
                                              const unsigned short* __restrict__ t5Wl,
                                              const float* __restrict__ t5b,
                                              const float* __restrict__ A2,
                                              const float* __restrict__ Bs2,
                                              const int* __restrict__ am){
  __shared__ __align__(16) unsigned short pnh[64*136];
  __shared__ __align__(16) unsigned short pnl[64*136];
  int t = threadIdx.x;
  long gbase = (long)blockIdx.x*64;
  ln_stage64(dp + gbase*128, en2s, en2b, pnh, pnl, t);
  __syncthreads();
  int w = t>>6, lane = t&63, l15 = lane&15, q = lane>>4;
  for(int mtl=0;mtl<2;mtl++){
    int mtg = w*2 + mtl;
    s16x8 afh[4], afl[4];
    for(int kt=0;kt<4;kt++){
      int wi = ((mtg*4+kt)*64 + lane)*8;
      afh[kt] = *(const s16x8*)(t5Wh + wi);
      afl[kt] = *(const s16x8*)(t5Wl + wi);
    }
    int e0 = mtg*16 + q*4;
    f32x4 t5b4 = *(const f32x4*)(t5b + e0);
    for(int nt=0;nt<4;nt++){
      f32x4 acc = (f32x4){0.f,0.f,0.f,0.f};
      for(int kt=0;kt<4;kt++){
        s16x8 bh = *(const s16x8*)&pnh[(nt*16+l15)*136 + kt*32 + q*8];
        s16x8 bl = *(const s16x8*)&pnl[(nt*16+l15)*136 + kt*32 + q*8];
        acc = MFMA(afh[kt], bh, acc);
        acc = MFMA(afh[kt], bl, acc);
        acc = MFMA(afl[kt], bh, acc);
      }
      long g = gbase + nt*16 + l15;
      int bb = (int)(g>>16), ii = ((int)(g>>8))&255, jj = (int)g&255;
      int msk = am[(bb*256+ii)*256 + jj];
      const float* A2p = A2 + (bb*256+jj)*128 + e0;
      const float* Bsp = Bs2 + (bb*256+ii)*128 + e0;
      f32x4 p1v = *(const f32x4*)(dp + g*128 + e0);
      f32x4 ov;
      for(int r=0;r<4;r++){
        float sg = 0.f;
        if(msk){
          float t56 = (acc[r] + t5b4[r]) * (A2p[r] + Bsp[r]);
          sg = sigmf(t56);
        }
        ov[r] = p1v[r] + sg;
      }
      *(f32x4*)(dp + g*128 + e0) = ov;
    }
  }
}

// ---------------- K8: p3 = p2 + gelu(LN(p2,en3)@effn1+b)@effn2 + b ----------------
// 32 rows/block (halves L2 weight traffic vs 16); GEMM1 3-term (pn hi/lo); h single bf16;
// GEMM2 2-term (W2 hi/lo); two-pass LN.
__global__ __launch_bounds__(256) void k8_effn(float* __restrict__ dp,
                                               const float* __restrict__ en3s,
                                               const float* __restrict__ en3b,
                                               const unsigned short* __restrict__ W1h,
                                               const unsigned short* __restrict__ W1l,
                                               const float* __restrict__ b1,
                                               const unsigned short* __restrict__ W2h,
                                               const unsigned short* __restrict__ W2l,
                                               const float* __restrict__ b2){
  __shared__ __align__(16) unsigned short pn3h[32*136];
  __shared__ __align__(16) unsigned short pn3l[32*136];
  __shared__ __align__(16) unsigned short hT[32*520];
  int t = threadIdx.x;
  long base = (long)blockIdx.x*32;
  { // phase A: LN(p2, en3) -> pn3 hi/lo (32 rows x 8 lanes, 16 ch/lane), two-pass
    int lr = t>>3, oct = t&7, e0 = oct*16;
    const float* pr = dp + (base+lr)*128 + e0;
    float v[16];
    for(int c=0;c<4;c++){ f32x4 u = *(const f32x4*)(pr + c*4); for(int r=0;r<4;r++) v[c*4+r] = u[r]; }
    float s = 0.f;
    for(int k=0;k<16;k++) s += v[k];
    s += __shfl_xor(s,1); s += __shfl_xor(s,2); s += __shfl_xor(s,4);
    float m = s*(1.f/128.f);
    float sq = 0.f;
    for(int k=0;k<16;k++){ float d = v[k]-m; sq += d*d; }
    sq += __shfl_xor(sq,1); sq += __shfl_xor(sq,2); sq += __shfl_xor(sq,4);
    float rstd = rsqrtf(sq*(1.f/128.f) + 1e-5f);
    for(int c=0;c<4;c++){
      f32x4 sv = *(const f32x4*)(en3s + e0 + c*4), bv = *(const f32x4*)(en3b + e0 + c*4);
      us4 vh, vl;
      for(int r=0;r<4;r++){
        float val = (v[c*4+r]-m)*rstd*sv[r] + bv[r];
        unsigned short h = f2b(val);
        vh[r] = h; vl[r] = f2b(val - b2f(h));
      }
      *(us4*)&pn3h[lr*136 + e0 + c*4] = vh;
      *(us4*)&pn3l[lr*136 + e0 + c*4] = vl;
    }
  }
  __syncthreads();
  int w = t>>6, lane = t&63, l15 = lane&15, q = lane>>4;
  { // GEMM1: hT = gelu(W1 * pn3^T + b1), 3-term; store single bf16
    s16x8 bh[2][4], bl[2][4];
    for(int nt=0;nt<2;nt++) for(int kt=0;kt<4;kt++){
      bh[nt][kt] = *(const s16x8*)&pn3h[(nt*16+l15)*136 + kt*32 + q*8];
      bl[nt][kt] = *(const s16x8*)&pn3l[(nt*16+l15)*136 + kt*32 + q*8];
    }
    for(int mtl=0;mtl<8;mtl++){
      int mtg = w*8 + mtl;
      s16x8 afh[4], afl[4];
      for(int kt=0;kt<4;kt++){
        afh[kt] = *(const s16x8*)(W1h + ((mtg*4+kt)*64 + lane)*8);
        afl[kt] = *(const s16x8*)(W1l + ((mtg*4+kt)*64 + lane)*8);
      }
      int col0 = mtg*16 + q*4;
      f32x4 bb = *(const f32x4*)(b1 + col0);
      for(int nt=0;nt<2;nt++){
        f32x4 acc = (f32x4){0.f,0.f,0.f,0.f};
        for(int kt=0;kt<4;kt++){
          acc = MFMA(afh[kt], bh[nt][kt], acc);
          acc = MFMA(afh[kt], bl[nt][kt], acc);
          acc = MFMA(afl[kt], bh[nt][kt], acc);
        }
        us4 hv;
        for(int r=0;r<4;r++) hv[r] = f2b(geluf(acc[r] + bb[r]));
        *(us4*)&hT[(nt*16+l15)*520 + col0] = hv;
      }
    }
  }
  __syncthreads();
  { // GEMM2: out = p2 + W2 * hT^T + b2, 2-term (h single x W2 hi/lo)
    f32x4 acc2[2][2];
    for(int a=0;a<2;a++) for(int n=0;n<2;n++) acc2[a][n] = (f32x4){0.f,0.f,0.f,0.f};
    for(int kt=0;kt<16;kt++){
      s16x8 bfr[2];
      for(int nt=0;nt<2;nt++) bfr[nt] = *(const s16x8*)&hT[(nt*16+l15)*520 + kt*32 + q*8];
      for(int mtl=0;mtl<2;mtl++){
        int m2 = w*2 + mtl;
        s16x8 ah = *(const s16x8*)(W2h + ((m2*16+kt)*64 + lane)*8);
        s16x8 al = *(const s16x8*)(W2l + ((m2*16+kt)*64 + lane)*8);
        for(int nt=0;nt<2;nt++){
          acc2[mtl][nt] = MFMA(ah, bfr[nt], acc2[mtl][nt]);
          acc2[mtl][nt] = MFMA(al, bfr[nt], acc2[mtl][nt]);
        }
      }
    }
    for(int mtl=0;mtl<2;mtl++){
      int m2 = w*2 + mtl;
      int col0 = m2*16 + q*4;
      f32x4 bb = *(const f32x4*)(b2 + col0);
      for(int nt=0;nt<2;nt++){
        long g = base + nt*16 + l15;
        f32x4 p2v = *(const f32x4*)(dp + g*128 + col0);
        f32x4 ov;
        for(int r=0;r<4;r++) ov[r] = p2v[r] + acc2[mtl][nt][r] + bb[r];
        *(f32x4*)(dp + g*128 + col0) = ov;
      }
    }
  }
}

extern "C" void kernel_launch(void* const* d_in, const int* in_sizes, int n_in,
                              void* d_out, int out_size, void* d_ws, size_t ws_size,
                              hipStream_t stream) {
  const float* x      = (const float*)d_in[0];
  const float* p      = (const float*)d_in[1];
  const int*   am     = (const int*)d_in[2];
  const float* nffn1W = (const float*)d_in[7];
  const float* nffn1b = (const float*)d_in[8];
  const float* nffn2W = (const float*)d_in[9];
  const float* nffn2b = (const float*)d_in[10];
  const float* o12W   = (const float*)d_in[11];
  const float* o12b   = (const float*)d_in[12];
  const float* o3W    = (const float*)d_in[13];
  const float* o3b    = (const float*)d_in[14];
  const float* tW     = (const float*)d_in[15];
  const float* tb     = (const float*)d_in[16];
  const float* t5W    = (const float*)d_in[17];
  const float* t5b    = (const float*)d_in[18];
  const float* t6W    = (const float*)d_in[19];
  const float* t6b    = (const float*)d_in[20];
  const float* e1W    = (const float*)d_in[21];
  const float* e1b    = (const float*)d_in[22];
  const float* e2W    = (const float*)d_in[23];
  const float* e2b    = (const float*)d_in[24];
  const float* n2s    = (const float*)d_in[27];
  const float* n2b    = (const float*)d_in[28];
  const float* en1s   = (const float*)d_in[29];
  const float* en1b   = (const float*)d_in[30];
  const float* en2s   = (const float*)d_in[31];
  const float* en2b   = (const float*)d_in[32];
  const float* en3s   = (const float*)d_in[33];
  const float* en3b   = (const float*)d_in[34];

  float* ox  = (float*)d_out;            // x out: 262144 f32
  float* opx = (float*)d_out + 262144;   // p out: 16777216 f32

  // Persistent workspace: first 1.65 MB of d_ws, zeroed at launch start.
  char* ws = (char*)d_ws;
  float* o1w    = (float*)(ws + 0);        // -> 8192
  float* o2w    = (float*)(ws + 8192);     // -> 16384
  float* A2     = (float*)(ws + 16384);    // -> 278528
  float* Bs2    = (float*)(ws + 278528);   // -> 540672
  unsigned short* t5Wh = (unsigned short*)(ws + 540672);   // -> 573440
  unsigned short* t5Wl = (unsigned short*)(ws + 573440);   // -> 606208
  unsigned short* W1h  = (unsigned short*)(ws + 606208);   // -> 737280
  unsigned short* W1l  = (unsigned short*)(ws + 737280);   // -> 868352
  unsigned short* W2h  = (unsigned short*)(ws + 868352);   // -> 999424
  unsigned short* W2l  = (unsigned short*)(ws + 999424);   // -> 1130496
  float* a_part  = (float*)(ws + 1130496); // -> 1392640
  float* bs_part = (float*)(ws + 1392640); // -> 1654784

  // fp32 x-path scratch in the dead head of the p-output region (fully
  // overwritten by k5 before any of opx is consumed as output).
  char* sc = (char*)opx;
  float* xnf    = (float*)(sc + 0);         // 1 MB
  float* hf     = (float*)(sc + 1048576);   // 4 MB -> 5242880
  float* gpart  = (float*)(sc + 5242880);   // 8 MB (k2 partials 2x4MB, then k3 partials 8x1MB) -> 13631488

  k_zero<<<404, 256, 0, stream>>>((float*)ws);   // 404*256*16B = 1654784 B

  k_repack2<<<8,   256, 0, stream>>>(t5W, t5Wh, t5Wl, 128, 2, 2048);
  k_repack2<<<32,  256, 0, stream>>>(e1W, W1h, W1l, 512, 2, 8192);
  k_repack2<<<32,  256, 0, stream>>>(e2W, W2h, W2l, 128, 4, 8192);

  k1_ln<<<512, 256, 0, stream>>>(x, n2s, n2b, xnf);
  k2s<<<dim3(16,32,2), 256, 0, stream>>>(xnf, nffn1W, gpart);
  k2e<<<1024, 256, 0, stream>>>(gpart, nffn1b, hf);
  k3s<<<dim3(4,32,8), 256, 0, stream>>>(hf, nffn2W, gpart);
  k3e<<<256, 256, 0, stream>>>(gpart, nffn2b, x, ox);
  k4_o12<<<512, 256, 0, stream>>>(ox, en1s, en1b, o12W, o12b, o1w, o2w);

  k5_p1<<<8192, 256, 0, stream>>>(p, o3W, o3b, o1w, o2w, opx);
  k7a_tt<<<2048, 256, 0, stream>>>(opx, en2s, en2b, tW, tb, am, a_part, bs_part);
  k6b<<<512, 128, 0, stream>>>(a_part, bs_part, t6W, t6b, A2, Bs2);
  k7b_p2<<<2048, 256, 0, stream>>>(opx, en2s, en2b, t5Wh, t5Wl, t5b, A2, Bs2, am);
  k8_effn<<<4096, 256, 0, stream>>>(opx, en3s, en3b, W1h, W1l, e1b, W2h, W2l, e2b);
}